// Round 3
// baseline (190.890 us; speedup 1.0000x reference)
//
#include <hip/hip_runtime.h>
#include <cstddef>

// Problem constants
constexpr int T_STEPS = 128;
constexpr int BATCH   = 64;
constexpr int N_IN    = 1024;
constexpr int N_OUT   = 1024;
constexpr int M_TOTAL = T_STEPS * BATCH;     // 8192 GEMM rows
constexpr int NEURONS = BATCH * N_OUT;       // 65536
constexpr int OUT_HALF = T_STEPS * NEURONS;  // 8388608 floats per output tensor

// Exact-arithmetic scheme: q = rint(W * 2^34), |q| <= 0.0902*2^34 = 1.55e9 < 2^31.
// 3 balanced radix-2048 digits d0,d1,d2 in [-1024,1023]; exact in f16 (11-bit mantissa).
// Per-plane GEMM sums <= 1024*1024 = 2^20 < 2^24 -> fp32 MFMA accumulation is EXACT.
// Recombine in fp64 (exact, < 2^53); cur = q_sum * 2^-34 (exact scale).
// Total quantization error <= ~205 * 2^-35 ~ 6e-9 per cur element.
constexpr double W_SCALE     = 17179869184.0;   // 2^34
constexpr double W_INV_SCALE = 1.0 / 17179869184.0;

typedef _Float16 f16x8 __attribute__((ext_vector_type(8)));
typedef float    f32x4 __attribute__((ext_vector_type(4)));

// ---------------- prep: x (fp32 {0,1}) -> f16 ----------------
__global__ __launch_bounds__(256)
void prep_x(const float* __restrict__ x, _Float16* __restrict__ xh)
{
    const int i = blockIdx.x * 256 + threadIdx.x;        // 1,048,576 threads, 8 floats each
    const float4 a = ((const float4*)x)[2 * i];
    const float4 b = ((const float4*)x)[2 * i + 1];
    f16x8 v;
    v[0] = (_Float16)a.x; v[1] = (_Float16)a.y; v[2] = (_Float16)a.z; v[3] = (_Float16)a.w;
    v[4] = (_Float16)b.x; v[5] = (_Float16)b.y; v[6] = (_Float16)b.z; v[7] = (_Float16)b.w;
    ((f16x8*)xh)[i] = v;
}

// ---------------- prep: W -> 3 digit planes (f16) ----------------
__global__ __launch_bounds__(256)
void prep_planes(const float* __restrict__ W, _Float16* __restrict__ ph)
{
    const int i = blockIdx.x * 256 + threadIdx.x;        // 1,048,576 threads
    const float w = W[i];
    int q = __double2int_rn((double)w * W_SCALE);        // exact round-to-nearest
    const int d0 = ((q + 1024) & 2047) - 1024;  q = (q - d0) >> 11;
    const int d1 = ((q + 1024) & 2047) - 1024;  q = (q - d1) >> 11;
    const int d2 = q;                                    // |d2| <= ~370
    ph[i]           = (_Float16)(float)d0;
    ph[1048576 + i] = (_Float16)(float)d1;
    ph[2097152 + i] = (_Float16)(float)d2;
}

// ---------------- exact 3-plane f16 MFMA GEMM ----------------
// C_p[m][o] = sum_k xh[m][k] * plane_p[o][k]  (NT, both row-major K-contiguous)
// 128x128 tile, BK=32, 512 threads (8 waves as 2Mx4N, wave tile 64x32).
// mfma_f32_16x16x32_f16 fragments (guide §3, m89-verified C/D):
//   A: row = lane&15, k = (lane>>4)*8 + j   (8 contiguous k per lane)
//   B: col = lane&15, k = (lane>>4)*8 + j
//   D: col = lane&15, row = (lane>>4)*4 + reg
// Epilogue: exact fp64 recombine, then store the double's lo32 word in the
// spk[t,n] output slot and hi32 word in the mem[t,n] slot. The scan thread
// owning (n) reads both words of (t,n) and later overwrites exactly those two
// slots -> per-thread, per-element in-place; race-free by construction.
constexpr int LDT = 40;   // padded row length in halves (80 B rows, 16B-aligned)

__global__ __launch_bounds__(512)
void gemm_planes(const _Float16* __restrict__ xh, const _Float16* __restrict__ ph,
                 unsigned* __restrict__ outw)   // d_out as 32-bit words
{
    __shared__ __align__(16) _Float16 As[128][LDT];
    __shared__ __align__(16) _Float16 Bs[3][128][LDT];

    const int tid  = threadIdx.x;
    const int m0   = blockIdx.x * 128;
    const int n0   = blockIdx.y * 128;
    const int lane = tid & 63;
    const int w    = tid >> 6;
    const int wm   = w >> 2;          // 0..1
    const int wn   = w & 3;           // 0..3
    const int l15  = lane & 15;
    const int kg   = lane >> 4;       // 0..3

    f32x4 acc[3][4][2] = {};

    const int arow = tid >> 2;        // A staging: 128 rows x 4 chunks of 8 halves
    const int aq   = tid & 3;

    for (int k0 = 0; k0 < N_IN; k0 += 32) {
        {   // stage A tile (exact f16 {0,1})
            const f16x8 v = *(const f16x8*)(xh + (size_t)(m0 + arow) * N_IN + k0 + aq * 8);
            *(f16x8*)(&As[arow][aq * 8]) = v;
        }
#pragma unroll
        for (int r = 0; r < 3; ++r) {   // stage 3 B digit planes
            const int u2  = tid + 512 * r;
            const int p   = u2 >> 9;
            const int rem = u2 & 511;
            const int row = rem >> 2;
            const int qq  = rem & 3;
            const f16x8 v = *(const f16x8*)(ph + (size_t)p * 1048576
                                              + (size_t)(n0 + row) * N_IN + k0 + qq * 8);
            *(f16x8*)(&Bs[p][row][qq * 8]) = v;
        }
        __syncthreads();

        f16x8 af[4], bf[2][3];
#pragma unroll
        for (int fm = 0; fm < 4; ++fm)
            af[fm] = *(const f16x8*)(&As[wm * 64 + fm * 16 + l15][kg * 8]);
#pragma unroll
        for (int fn = 0; fn < 2; ++fn)
#pragma unroll
            for (int p = 0; p < 3; ++p)
                bf[fn][p] = *(const f16x8*)(&Bs[p][wn * 32 + fn * 16 + l15][kg * 8]);

#pragma unroll
        for (int p = 0; p < 3; ++p)
#pragma unroll
            for (int fm = 0; fm < 4; ++fm)
#pragma unroll
                for (int fn = 0; fn < 2; ++fn)
                    acc[p][fm][fn] = __builtin_amdgcn_mfma_f32_16x16x32_f16(
                        af[fm], bf[fn][p], acc[p][fm][fn], 0, 0, 0);
        __syncthreads();
    }

    // epilogue: exact recombine -> fp64 cur, split hi/lo across the two output slots
#pragma unroll
    for (int fm = 0; fm < 4; ++fm)
#pragma unroll
        for (int fn = 0; fn < 2; ++fn)
#pragma unroll
            for (int r = 0; r < 4; ++r) {
                const int m = m0 + wm * 64 + fm * 16 + kg * 4 + r;   // D row
                const int o = n0 + wn * 32 + fn * 16 + l15;          // D col
                const double q = (double)acc[2][fm][fn][r] * 4194304.0
                               + (double)acc[1][fm][fn][r] * 2048.0
                               + (double)acc[0][fm][fn][r];
                const double cur = q * W_INV_SCALE;
                const unsigned long long u = (unsigned long long)__double_as_longlong(cur);
                const int t = m >> 6;            // m = t*64 + b
                const int b = m & 63;
                const size_t idx = (size_t)t * NEURONS + (size_t)b * N_OUT + o;
                outw[idx]            = (unsigned)u;           // lo32 in spk slot
                outw[OUT_HALF + idx] = (unsigned)(u >> 32);   // hi32 in mem slot
            }
}

// ---------------- fp64 LIF scan, per-thread in-place over d_out ----------------
// All aliased accesses via unsigned* (float results stored as bit patterns) so
// strict aliasing cannot reorder the cur-loads vs output-stores.
__global__ __launch_bounds__(256)
void lif_scan(unsigned* outw)
{
    const int n = blockIdx.x * 256 + threadIdx.x;        // 0..65535
    double mem = 0.0;
    double c[8];
    for (int t0 = 0; t0 < T_STEPS; t0 += 8) {
#pragma unroll
        for (int j = 0; j < 8; ++j) {
            const size_t idx = (size_t)(t0 + j) * NEURONS + n;
            const unsigned lo = outw[idx];
            const unsigned hi = outw[OUT_HALF + idx];
            c[j] = __longlong_as_double(
                (long long)(((unsigned long long)hi << 32) | lo));
        }
#pragma unroll
        for (int j = 0; j < 8; ++j) {
            const double reset = (mem > 1.0) ? 1.0 : 0.0;   // spike of previous mem
            mem = 0.9 * mem + c[j] - reset;                 // subtract-reset, thr=1
            const size_t idx = (size_t)(t0 + j) * NEURONS + n;
            outw[idx]            = (mem > 1.0) ? 0x3f800000u : 0u;  // spk as float bits
            outw[OUT_HALF + idx] = __float_as_uint((float)mem);     // mem_rec fp32
        }
    }
}

extern "C" void kernel_launch(void* const* d_in, const int* in_sizes, int n_in,
                              void* d_out, int out_size, void* d_ws, size_t ws_size,
                              hipStream_t stream)
{
    const float* x = (const float*)d_in[0];   // (128,64,1024)
    const float* W = (const float*)d_in[1];   // (1024,1024)
    unsigned* outw = (unsigned*)d_out;

    _Float16* xh = (_Float16*)d_ws;                                       // 16.78 MB
    _Float16* ph = (_Float16*)((char*)d_ws + (size_t)M_TOTAL * N_IN * 2); // 3 x 2 MB

    prep_x<<<4096, 256, 0, stream>>>(x, xh);
    prep_planes<<<4096, 256, 0, stream>>>(W, ph);

    dim3 ggrid(M_TOTAL / 128, N_OUT / 128);   // 64 x 8
    gemm_planes<<<ggrid, 512, 0, stream>>>(xh, ph, outw);

    lif_scan<<<NEURONS / 256, 256, 0, stream>>>(outw);
}

// Round 4
// 161.025 us; speedup vs baseline: 1.1855x; 1.1855x over previous
//
#include <hip/hip_runtime.h>
#include <cstddef>

// Problem constants
constexpr int T_STEPS = 128;
constexpr int BATCH   = 64;
constexpr int N_IN    = 1024;
constexpr int N_OUT   = 1024;
constexpr int M_TOTAL = T_STEPS * BATCH;     // 8192 GEMM rows
constexpr int NEURONS = BATCH * N_OUT;       // 65536
constexpr int OUT_HALF = T_STEPS * NEURONS;  // 8388608 floats per output tensor

// Exact-arithmetic scheme (UNCHANGED q from the passing round):
//   q = rint(W * 2^34), |q| <= 0.0902*2^34 = 1.55e9 < 2^31.
// NEW decomposition: 4 balanced radix-256 digits d0..d3 in [-128,127] (exact i8).
//   q = d3*2^24 + d2*2^16 + d1*2^8 + d0.
// x in {0,1} exact in i8; per-plane GEMM sums |.| <= 1024*128 = 2^17, exact in the
// i32 MFMA accumulator (always exact). Recombine in fp64: |q_sum| < 2^42 exact,
// cur = q_sum * 2^-34 exact. => bit-identical cur/outputs vs round 3.
constexpr double W_SCALE     = 17179869184.0;   // 2^34
constexpr double W_INV_SCALE = 1.0 / 17179869184.0;

typedef int   i32x4 __attribute__((ext_vector_type(4)));
typedef float f32x4 __attribute__((ext_vector_type(4)));

// ---------------- fused prep: x -> i8, W -> 4 i8 digit planes ----------------
// blocks [0,2048): x path, 16 elements/thread. blocks [2048,3072): W path, 4 wts/thread.
__global__ __launch_bounds__(256)
void prep_all(const float* __restrict__ x, const float* __restrict__ W,
              signed char* __restrict__ xi8, signed char* __restrict__ pi8)
{
    const int bid = blockIdx.x;
    if (bid < 2048) {
        const int i = bid * 256 + threadIdx.x;           // 0..524287, 16 floats each
        const float4 a = ((const float4*)x)[4 * i + 0];
        const float4 b = ((const float4*)x)[4 * i + 1];
        const float4 c = ((const float4*)x)[4 * i + 2];
        const float4 d = ((const float4*)x)[4 * i + 3];
        const float f[16] = {a.x,a.y,a.z,a.w, b.x,b.y,b.z,b.w,
                             c.x,c.y,c.z,c.w, d.x,d.y,d.z,d.w};
        union { signed char b[16]; int4 v; } u;
#pragma unroll
        for (int j = 0; j < 16; ++j) u.b[j] = (signed char)(f[j] != 0.0f);
        ((int4*)xi8)[i] = u.v;
    } else {
        const int i = (bid - 2048) * 256 + threadIdx.x;  // 0..262143, 4 weights each
        const float4 wv = ((const float4*)W)[i];
        const float wf[4] = {wv.x, wv.y, wv.z, wv.w};
        union { signed char b[4]; unsigned u; } dig[4];
#pragma unroll
        for (int j = 0; j < 4; ++j) {
            int q = __double2int_rn((double)wf[j] * W_SCALE);   // exact rint
            const int d0 = ((q + 128) & 255) - 128;  q = (q - d0) >> 8;
            const int d1 = ((q + 128) & 255) - 128;  q = (q - d1) >> 8;
            const int d2 = ((q + 128) & 255) - 128;  q = (q - d2) >> 8;
            dig[0].b[j] = (signed char)d0;
            dig[1].b[j] = (signed char)d1;
            dig[2].b[j] = (signed char)d2;
            dig[3].b[j] = (signed char)q;                       // |d3| <= ~93
        }
        unsigned* pw = (unsigned*)pi8;
#pragma unroll
        for (int p = 0; p < 4; ++p) pw[p * 262144 + i] = dig[p].u;
    }
}

// ---------------- exact 4-plane i8 MFMA GEMM ----------------
// C_p[m][o] = sum_k xi8[m][k] * plane_p[o][k]  (NT, K-contiguous), i32 exact.
// 128x128 tile, BK=64, 512 threads (8 waves as 2Mx4N, wave tile 64x32).
// mfma_i32_16x16x64_i8 fragments (K-doubled analog of HW-verified f16 maps):
//   A: row = lane&15, k = (lane>>4)*16 + j   (16 consecutive k bytes per lane)
//   B: col = lane&15, k = (lane>>4)*16 + j
//   D: col = lane&15, row = (lane>>4)*4 + reg   (shape-determined, dtype-indep)
constexpr int LDT = 80;   // padded row length in bytes (2-way LDS alias only = free)

__global__ __launch_bounds__(512)
void gemm_planes(const signed char* __restrict__ xi8, const signed char* __restrict__ pi8,
                 unsigned* __restrict__ outw)   // d_out as 32-bit words
{
    __shared__ __align__(16) signed char As[128][LDT];
    __shared__ __align__(16) signed char Bs[4][128][LDT];

    const int tid  = threadIdx.x;
    const int m0   = blockIdx.x * 128;
    const int n0   = blockIdx.y * 128;
    const int lane = tid & 63;
    const int w    = tid >> 6;
    const int wm   = w >> 2;          // 0..1
    const int wn   = w & 3;           // 0..3
    const int l15  = lane & 15;
    const int kg   = lane >> 4;       // 0..3

    i32x4 acc[4][4][2] = {};

    const int arow = tid >> 2;        // A staging: 128 rows x 4 chunks of 16 bytes
    const int aq   = tid & 3;

    for (int k0 = 0; k0 < N_IN; k0 += 64) {
        {   // stage A tile (8 KB)
            const int4 v = *(const int4*)(xi8 + (size_t)(m0 + arow) * N_IN + k0 + aq * 16);
            *(int4*)(&As[arow][aq * 16]) = v;
        }
#pragma unroll
        for (int r = 0; r < 4; ++r) {   // stage 4 B digit planes (32 KB)
            const int u2  = tid + 512 * r;
            const int p   = u2 >> 9;
            const int rem = u2 & 511;
            const int row = rem >> 2;
            const int qq  = rem & 3;
            const int4 v = *(const int4*)(pi8 + (size_t)p * 1048576
                                              + (size_t)(n0 + row) * N_IN + k0 + qq * 16);
            *(int4*)(&Bs[p][row][qq * 16]) = v;
        }
        __syncthreads();

        i32x4 af[4], bf[2][4];
#pragma unroll
        for (int fm = 0; fm < 4; ++fm)
            af[fm] = *(const i32x4*)(&As[wm * 64 + fm * 16 + l15][kg * 16]);
#pragma unroll
        for (int fn = 0; fn < 2; ++fn)
#pragma unroll
            for (int p = 0; p < 4; ++p)
                bf[fn][p] = *(const i32x4*)(&Bs[p][wn * 32 + fn * 16 + l15][kg * 16]);

#pragma unroll
        for (int p = 0; p < 4; ++p)
#pragma unroll
            for (int fm = 0; fm < 4; ++fm)
#pragma unroll
                for (int fn = 0; fn < 2; ++fn)
                    acc[p][fm][fn] = __builtin_amdgcn_mfma_i32_16x16x64_i8(
                        af[fm], bf[fn][p], acc[p][fm][fn], 0, 0, 0);
        __syncthreads();
    }

    // epilogue: exact fp64 recombine; store double's lo32 in spk slot, hi32 in mem
    // slot (per-thread in-place overlay -> race-free vs the scan by construction).
#pragma unroll
    for (int fm = 0; fm < 4; ++fm)
#pragma unroll
        for (int fn = 0; fn < 2; ++fn)
#pragma unroll
            for (int r = 0; r < 4; ++r) {
                const int m = m0 + wm * 64 + fm * 16 + kg * 4 + r;   // D row
                const int o = n0 + wn * 32 + fn * 16 + l15;          // D col
                const double q = (double)acc[3][fm][fn][r] * 16777216.0
                               + (double)acc[2][fm][fn][r] * 65536.0
                               + (double)acc[1][fm][fn][r] * 256.0
                               + (double)acc[0][fm][fn][r];
                const double cur = q * W_INV_SCALE;
                const unsigned long long u = (unsigned long long)__double_as_longlong(cur);
                const int t = m >> 6;            // m = t*64 + b
                const int b = m & 63;
                const size_t idx = (size_t)t * NEURONS + (size_t)b * N_OUT + o;
                outw[idx]            = (unsigned)u;           // lo32 in spk slot
                outw[OUT_HALF + idx] = (unsigned)(u >> 32);   // hi32 in mem slot
            }
}

// ---------------- fp64 LIF scan, 2 neurons/thread, in-place over d_out ----------
__global__ __launch_bounds__(256)
void lif_scan(unsigned* outw)
{
    const int n = (blockIdx.x * 256 + threadIdx.x) * 2;  // even neuron index
    double mem0 = 0.0, mem1 = 0.0;
    double c0[8], c1[8];
    for (int t0 = 0; t0 < T_STEPS; t0 += 8) {
#pragma unroll
        for (int j = 0; j < 8; ++j) {
            const size_t idx = (size_t)(t0 + j) * NEURONS + n;
            const uint2 lo = *(const uint2*)(outw + idx);
            const uint2 hi = *(const uint2*)(outw + OUT_HALF + idx);
            c0[j] = __longlong_as_double((long long)(((unsigned long long)hi.x << 32) | lo.x));
            c1[j] = __longlong_as_double((long long)(((unsigned long long)hi.y << 32) | lo.y));
        }
#pragma unroll
        for (int j = 0; j < 8; ++j) {
            const double r0 = (mem0 > 1.0) ? 1.0 : 0.0;     // spike of previous mem
            const double r1 = (mem1 > 1.0) ? 1.0 : 0.0;
            mem0 = 0.9 * mem0 + c0[j] - r0;                 // subtract-reset, thr=1
            mem1 = 0.9 * mem1 + c1[j] - r1;
            const size_t idx = (size_t)(t0 + j) * NEURONS + n;
            uint2 s, mv;
            s.x  = (mem0 > 1.0) ? 0x3f800000u : 0u;
            s.y  = (mem1 > 1.0) ? 0x3f800000u : 0u;
            mv.x = __float_as_uint((float)mem0);
            mv.y = __float_as_uint((float)mem1);
            *(uint2*)(outw + idx)            = s;            // spk_rec
            *(uint2*)(outw + OUT_HALF + idx) = mv;           // mem_rec
        }
    }
}

extern "C" void kernel_launch(void* const* d_in, const int* in_sizes, int n_in,
                              void* d_out, int out_size, void* d_ws, size_t ws_size,
                              hipStream_t stream)
{
    const float* x = (const float*)d_in[0];   // (128,64,1024)
    const float* W = (const float*)d_in[1];   // (1024,1024)
    unsigned* outw = (unsigned*)d_out;

    signed char* xi8 = (signed char*)d_ws;                     // 8.39 MB
    signed char* pi8 = xi8 + (size_t)M_TOTAL * N_IN;           // 4 x 1 MB planes

    prep_all<<<3072, 256, 0, stream>>>(x, W, xi8, pi8);

    dim3 ggrid(M_TOTAL / 128, N_OUT / 128);   // 64 x 8
    gemm_planes<<<ggrid, 512, 0, stream>>>(xi8, pi8, outw);

    lif_scan<<<NEURONS / 512, 256, 0, stream>>>(outw);
}